// Round 6
// baseline (614.590 us; speedup 1.0000x reference)
//
#include <hip/hip_runtime.h>
#include <math.h>

#define NTOT 16384
#define NSEG 2048

// ws float offsets
#define OFF_HH   0ull         // hh [4][8][2048][64] = 4194304 (hc [8][2048][64] reuses)
#define OFF_XC   4194304ull   // xc [16384][256] = 4194304
#define OFF_S1H  8388608ull
#define OFF_S2H  8454144ull
#define OFF_S1O  8519680ull
#define OFF_S2O  8536064ull
#define OFF_SVAL 8552448ull
#define OFF_WN   8617984ull
#define OFF_SIDX 8683520ull
#define OFF_VAS  8749056ull   // 32*129*128
#define OFF_CSA  9277440ull   // 32*129
#define OFF_CSS  9281568ull
#define OFF_SCA  9285696ull   // 32*2048
#define OFF_SCS  9351232ull
#define OFF_AS   9416768ull   // 32*2048*128 -> 17805376
#define OFF_CNT  17805376ull  // 512 ints: cnt1[32]@0 flag1[32]@128 cnt2[8]@256 flag2[8]@384
#define OFF_TAS  17805888ull  // 32*128*128 (no longer aliases xc!)
#define OFF_TSA  18330176ull  // 32*128
#define OFF_TSS  18334272ull  // 32*128 -> end 18338368 floats (73.4 MB)

__device__ inline unsigned long long pack_key(float v, int idx) {
    unsigned u = __float_as_uint(v);
    u = (u & 0x80000000u) ? ~u : (u | 0x80000000u);
    return ((unsigned long long)u << 32) | (unsigned)idx;
}
__device__ inline float unpack_key(unsigned long long k) {
    unsigned u = (unsigned)(k >> 32);
    u = (u & 0x80000000u) ? (u ^ 0x80000000u) : ~u;
    return __uint_as_float(u);
}
__device__ inline unsigned long long shfl_xor_u64(unsigned long long x, int mask) {
    unsigned lo = (unsigned)x, hi = (unsigned)(x >> 32);
    lo = (unsigned)__shfl_xor((int)lo, mask, 64);
    hi = (unsigned)__shfl_xor((int)hi, mask, 64);
    return ((unsigned long long)hi << 32) | lo;
}

// ---------------- GEMM 1 + fused s1/s2 projection; hh head-major; zeroes layer-1 counters ----------------
__global__ __launch_bounds__(256) void gemm1_k(const float* __restrict__ X,
                                               const float* __restrict__ Wh,
                                               const float* __restrict__ aH,
                                               float* __restrict__ hh,
                                               float* __restrict__ s1h,
                                               float* __restrict__ s2h,
                                               int* __restrict__ cntbase) {
    __shared__ float As[64][68];
    __shared__ float Bs[64][68];
    const int tid = threadIdx.x;
    const int bm = blockIdx.x, h = blockIdx.y;
    if (bm == 0 && h == 0 && tid < 160) cntbase[tid] = 0;   // cnt1[0..31], flag1[128..159]
    const int c0 = tid & 63, r0 = tid >> 6;
#pragma unroll
    for (int r = 0; r < 16; ++r) {
        int row = r0 + r * 4;
        As[c0][row] = X[(size_t)(bm * 64 + row) * 64 + c0];
        Bs[row][c0] = Wh[h * 4096 + row * 64 + c0];
    }
    __syncthreads();
    const int tx = tid & 15, ty = tid >> 4;
    const int m0 = ty * 4, n0 = tx * 4;
    float acc[4][4] = {};
#pragma unroll
    for (int kk = 0; kk < 64; ++kk) {
        float4 a = *(const float4*)&As[kk][m0];
        float4 b = *(const float4*)&Bs[kk][n0];
        acc[0][0] += a.x * b.x; acc[0][1] += a.x * b.y; acc[0][2] += a.x * b.z; acc[0][3] += a.x * b.w;
        acc[1][0] += a.y * b.x; acc[1][1] += a.y * b.y; acc[1][2] += a.y * b.z; acc[1][3] += a.y * b.w;
        acc[2][0] += a.z * b.x; acc[2][1] += a.z * b.y; acc[2][2] += a.z * b.z; acc[2][3] += a.z * b.w;
        acc[3][0] += a.w * b.x; acc[3][1] += a.w * b.y; acc[3][2] += a.w * b.z; acc[3][3] += a.w * b.w;
    }
    const int g = bm >> 5;
    const int nb = (bm * 64) & 2047;
#pragma unroll
    for (int i = 0; i < 4; ++i) {
        float4 v = make_float4(acc[i][0], acc[i][1], acc[i][2], acc[i][3]);
        *(float4*)&hh[(((size_t)h * 8 + g) * NSEG + nb + m0 + i) * 64 + n0] = v;
    }
#pragma unroll
    for (int i = 0; i < 4; ++i) {
        float p1 = 0.f, p2 = 0.f;
#pragma unroll
        for (int jj = 0; jj < 4; ++jj) {
            p1 += acc[i][jj] * aH[h * 128 + n0 + jj];
            p2 += acc[i][jj] * aH[h * 128 + 64 + n0 + jj];
        }
#pragma unroll
        for (int off = 8; off; off >>= 1) {
            p1 += __shfl_xor(p1, off, 16);
            p2 += __shfl_xor(p2, off, 16);
        }
        if (tx == 0) {
            s1h[h * NTOT + bm * 64 + m0 + i] = p1;
            s2h[h * NTOT + bm * 64 + m0 + i] = p2;
        }
    }
}

// ---------------- GEMM 2 (BM=32, 512 blocks) + s1/s2; zeroes layer-2 counters ----------------
__global__ __launch_bounds__(256) void gemm2_k(const float* __restrict__ XC,
                                               const float* __restrict__ Wo,
                                               const float* __restrict__ aO,
                                               float* __restrict__ hc,
                                               float* __restrict__ s1o,
                                               float* __restrict__ s2o,
                                               int* __restrict__ cnt2base) {
    __shared__ float As[64][34];
    __shared__ float Bs[64][68];
    const int tid = threadIdx.x;
    const int bm = blockIdx.x;
    if (bm == 0 && tid < 136) cnt2base[tid] = 0;            // cnt2[0..7], flag2[128..135]
    const int c0 = tid & 63, r0 = tid >> 6;
    const int tx = tid & 15, ty = tid >> 4;
    const int m0 = ty * 2, n0 = tx * 4;
    float acc[2][4] = {};
    for (int kt = 0; kt < 4; ++kt) {
#pragma unroll
        for (int r = 0; r < 8; ++r) {
            int row = r0 + r * 4;
            As[c0][row] = XC[(size_t)(bm * 32 + row) * 256 + kt * 64 + c0];
        }
#pragma unroll
        for (int r = 0; r < 16; ++r) {
            int row = r0 + r * 4;
            Bs[row][c0] = Wo[(kt * 64 + row) * 64 + c0];
        }
        __syncthreads();
#pragma unroll
        for (int kk = 0; kk < 64; ++kk) {
            float2 a = *(const float2*)&As[kk][m0];
            float4 b = *(const float4*)&Bs[kk][n0];
            acc[0][0] += a.x * b.x; acc[0][1] += a.x * b.y; acc[0][2] += a.x * b.z; acc[0][3] += a.x * b.w;
            acc[1][0] += a.y * b.x; acc[1][1] += a.y * b.y; acc[1][2] += a.y * b.z; acc[1][3] += a.y * b.w;
        }
        __syncthreads();
    }
#pragma unroll
    for (int i = 0; i < 2; ++i) {
        float4 v = make_float4(acc[i][0], acc[i][1], acc[i][2], acc[i][3]);
        *(float4*)&hc[(size_t)(bm * 32 + m0 + i) * 64 + n0] = v;
    }
#pragma unroll
    for (int i = 0; i < 2; ++i) {
        float p1 = 0.f, p2 = 0.f;
#pragma unroll
        for (int jj = 0; jj < 4; ++jj) {
            p1 += acc[i][jj] * aO[n0 + jj];
            p2 += acc[i][jj] * aO[64 + n0 + jj];
        }
#pragma unroll
        for (int off = 8; off; off >>= 1) {
            p1 += __shfl_xor(p1, off, 16);
            p2 += __shfl_xor(p2, off, 16);
        }
        if (tx == 0) {
            s1o[bm * 32 + m0 + i] = p1;
            s2o[bm * 32 + m0 + i] = p2;
        }
    }
}

// ---------------- lean bitonic sort: 1 block per task ----------------
__global__ __launch_bounds__(1024) void sort_k(const float* __restrict__ s2_all,
                                               int heads,
                                               float* __restrict__ g_sval,
                                               int* __restrict__ g_sidx,
                                               float* __restrict__ g_wN) {
    __shared__ unsigned long long sA[2][1024];
    __shared__ unsigned long long sB[2][1024];
    __shared__ float sM2;
    const int tid = threadIdx.x, t = blockIdx.x;
    const int g = t / heads, h = t % heads;
    const float* s2p = s2_all + (size_t)h * NTOT + (size_t)g * NSEG;

    unsigned long long a0 = pack_key(s2p[tid], tid);
    unsigned long long a1 = pack_key(s2p[tid + 1024], tid + 1024);
    int p = 0;
    for (int k = 2; k <= 2048; k <<= 1) {
        const bool up0 = (tid & k) == 0;
        const bool up1 = (((tid + 1024) & k) == 0);
        for (int j = k >> 1; j > 0; j >>= 1) {
            if (j >= 1024) {
                unsigned long long lo = a0 < a1 ? a0 : a1;
                unsigned long long hi = a0 < a1 ? a1 : a0;
                a0 = up0 ? lo : hi;
                a1 = up0 ? hi : lo;
            } else if (j >= 64) {
                sA[p][tid] = a0; sB[p][tid] = a1;
                __syncthreads();
                unsigned long long q0 = sA[p][tid ^ j], q1 = sB[p][tid ^ j];
                bool lower = (tid & j) == 0;
                a0 = ((a0 < q0) == (lower == up0)) ? a0 : q0;
                a1 = ((a1 < q1) == (lower == up1)) ? a1 : q1;
                p ^= 1;
            } else {
                unsigned long long q0 = shfl_xor_u64(a0, j);
                unsigned long long q1 = shfl_xor_u64(a1, j);
                bool lower = (tid & j) == 0;
                a0 = ((a0 < q0) == (lower == up0)) ? a0 : q0;
                a1 = ((a1 < q1) == (lower == up1)) ? a1 : q1;
            }
        }
    }
    float v0 = unpack_key(a0), v1 = unpack_key(a1);
    if (tid == 1023) sM2 = v1;
    __syncthreads();
    const float M2 = sM2;
    int i0 = (int)(unsigned)(a0 & 0xffffffffu);
    int i1 = (int)(unsigned)(a1 & 0xffffffffu);
    float w0 = __expf(0.2f * (v0 - M2));
    float w1 = __expf(0.2f * (v1 - M2));
    size_t o = (size_t)t * NSEG;
    g_sval[o + tid] = v0; g_sval[o + tid + 1024] = v1;
    g_sidx[o + tid] = i0; g_sidx[o + tid + 1024] = i1;
    g_wN[o + tid] = w0;   g_wN[o + tid + 1024] = w1;
}

// ---------------- bodies (identical arithmetic to R4) ----------------
__device__ __forceinline__ void tabw_body(const float* __restrict__ Vp, int t, int c, int lane,
                                          const int* __restrict__ g_sidx, const float* __restrict__ g_wN,
                                          float* __restrict__ AS,
                                          float* __restrict__ SCA, float* __restrict__ SCS,
                                          float* __restrict__ TAS,
                                          float* __restrict__ TSA, float* __restrict__ TSS) {
    const int base = c * 16;
    const int* sidx = g_sidx + (size_t)t * NSEG + base;
    const float* wnp = g_wN + (size_t)t * NSEG + base;
    float wn[16], vv[16];
#pragma unroll
    for (int j = 0; j < 16; ++j) wn[j] = wnp[j];
#pragma unroll
    for (int j = 0; j < 16; ++j) vv[j] = Vp[(size_t)sidx[j] * 64 + lane];
    float* ASp = AS + (size_t)t * NSEG * 128;
    float accA = 0.f, scaA = 0.f;
#pragma unroll
    for (int j = 0; j < 16; ++j) {
        size_t pos = base + j;
        ASp[pos * 128 + lane] = accA;
        if (lane == 0) SCA[(size_t)t * NSEG + pos] = scaA;
        accA += wn[j] * vv[j]; scaA += wn[j];
    }
    TAS[((size_t)t * 128 + c) * 128 + lane] = accA;
    if (lane == 0) TSA[t * 128 + c] = scaA;
    float accS = 0.f, scaS = 0.f;
#pragma unroll
    for (int j = 15; j >= 0; --j) {
        float wq = wn[j], w2 = wq * wq, wp = w2 * w2 * wq;
        accS += wp * vv[j]; scaS += wp;
        size_t pos = base + j;
        ASp[pos * 128 + 64 + lane] = accS;
        if (lane == 0) SCS[(size_t)t * NSEG + pos] = scaS;
    }
    TAS[((size_t)t * 128 + c) * 128 + 64 + lane] = accS;
    if (lane == 0) TSS[t * 128 + c] = scaS;
}

__device__ __forceinline__ void scan_body(int t, int tid,
                                          const float* __restrict__ TAS,
                                          const float* __restrict__ TSA, const float* __restrict__ TSS,
                                          float* __restrict__ VAS,
                                          float* __restrict__ CSA, float* __restrict__ CSS) {
    const float* T = TAS + (size_t)t * 128 * 128;
    float* Vo = VAS + (size_t)t * 129 * 128;
    if (tid < 64) {
        float run = 0.f;
#pragma unroll 4
        for (int c = 0; c < 128; ++c) { Vo[c * 128 + tid] = run; run += T[c * 128 + tid]; }
        Vo[128 * 128 + tid] = run;
    } else if (tid < 128) {
        float run = 0.f;
#pragma unroll 4
        for (int c = 127; c >= 0; --c) { Vo[c * 128 + tid] = run; run += T[c * 128 + tid]; }
    } else if (tid == 128) {
        float run = 0.f;
        for (int c = 0; c < 128; ++c) { CSA[t * 129 + c] = run; run += TSA[t * 128 + c]; }
        CSA[t * 129 + 128] = run;
    } else if (tid == 129) {
        float run = 0.f;
        for (int c = 127; c >= 0; --c) { CSS[t * 129 + c] = run; run += TSS[t * 128 + c]; }
    }
}

template <int MODE>
__device__ __forceinline__ void query_body(int t, int q0, int lane, float M2,
                                           const float* __restrict__ sval,
                                           const float* __restrict__ s1p,
                                           float* __restrict__ outp, int ostride,
                                           const float* __restrict__ AS,
                                           const float* __restrict__ SCA, const float* __restrict__ SCS,
                                           const float* __restrict__ VAS,
                                           const float* __restrict__ CSA, const float* __restrict__ CSS) {
    const float* ASp = AS + (size_t)t * NSEG * 128;
    const float* VASp = VAS + (size_t)t * 129 * 128;
    const float* scA = SCA + (size_t)t * NSEG;
    const float* scS = SCS + (size_t)t * NSEG;
    const float* csA = CSA + (size_t)t * 129;
    const float* csS = CSS + (size_t)t * 129;
    int myq = q0 + (lane & 15);
    float s1v = s1p[myq];
    float th = -s1v;
    int lo = 0, hi = NSEG;
    while (lo < hi) { int mid = (lo + hi) >> 1; if (sval[mid] <= th) lo = mid + 1; else hi = mid; }
#pragma unroll 4
    for (int j = 0; j < 16; ++j) {
        int k = __shfl(lo, j, 64);
        float s1q = __shfl(s1v, j, 64);
        float accA, scaA, accS, scaS;
        if (k < NSEG) {
            const int c = k >> 4;
            const float* rowP = ASp + (size_t)k * 128;
            const float* rowC = VASp + (size_t)c * 128;
            accA = rowP[lane] + rowC[lane];
            accS = rowP[64 + lane] + rowC[64 + lane];
            scaA = scA[k] + csA[c];
            scaS = scS[k] + csS[c];
        } else {
            accA = VASp[128 * 128 + lane]; scaA = csA[128];
            accS = 0.f; scaS = 0.f;
        }
        float cc = __expf(-0.8f * fmaxf(s1q + M2, 0.f));
        float o = (accS + cc * accA) / (scaS + cc * scaA);
        o = o > 0.f ? o : expm1f(o);  // ELU
        int q = q0 + j;
        if (MODE == 0) {
            outp[(size_t)q * ostride + lane] = o;
        } else {
            float m = o;
#pragma unroll
            for (int off = 32; off; off >>= 1) m = fmaxf(m, __shfl_xor(m, off, 64));
            float e = __expf(o - m);
#pragma unroll
            for (int off = 32; off; off >>= 1) e += __shfl_xor(e, off, 64);
            outp[(size_t)q * ostride + lane] = o - m - __logf(e);
        }
    }
}

// ---------------- fused tabw + per-task handshake + scan + query ----------------
template <int MODE>
__global__ __launch_bounds__(256) void fused_k(const float* __restrict__ V,
                                               int heads, int ntask,
                                               const int* __restrict__ g_sidx,
                                               const float* __restrict__ g_wN,
                                               float* __restrict__ AS,
                                               float* __restrict__ SCA, float* __restrict__ SCS,
                                               float* __restrict__ TAS,
                                               float* __restrict__ TSA, float* __restrict__ TSS,
                                               float* __restrict__ VAS,
                                               float* __restrict__ CSA, float* __restrict__ CSS,
                                               const float* __restrict__ s1_all,
                                               float* __restrict__ out, int ostride,
                                               const float* __restrict__ g_sval,
                                               int* __restrict__ cnt, int* __restrict__ flag) {
    __shared__ float sval[NSEG];
    __shared__ int s_last;
    const int tid = threadIdx.x;
    const int L = blockIdx.x;
    const int xcd = L & 7, slot = L >> 3;
    const int tpx = ntask >> 3;
    const int t = xcd * tpx + (slot >> 5);
    const int u = slot & 31;
    const int wv = tid >> 6, lane = tid & 63;
    const int g = t / heads, h = t % heads;
    const int seg = h * (ntask / heads) + g;
    const float* Vp = V + (size_t)seg * NSEG * 64;

    // ---- tabw: 4 chunks per block (wave wv -> chunk u*4+wv) ----
    tabw_body(Vp, t, u * 4 + wv, lane, g_sidx, g_wN, AS, SCA, SCS, TAS, TSA, TSS);

    // overlap: stage sval while other blocks finish tabw
    const float4* sv4 = (const float4*)(g_sval + (size_t)t * NSEG);
    for (int i = tid; i < NSEG / 4; i += 256) ((float4*)sval)[i] = sv4[i];

    // ---- per-task handshake: 32 arrivals -> last block scans -> flag release ----
    __threadfence();             // each thread's table stores visible device-wide
    __syncthreads();
    if (tid == 0) {
        int old = atomicAdd(&cnt[t], 1);
        s_last = (old == 31) ? 1 : 0;
    }
    __syncthreads();
    if (s_last) {
        __threadfence();         // acquire: peers' TAS/TSA/TSS
        scan_body(t, tid, TAS, TSA, TSS, VAS, CSA, CSS);
        __threadfence();         // release scan results
        __syncthreads();
        if (tid == 0) __hip_atomic_store(&flag[t], 1, __ATOMIC_RELEASE, __HIP_MEMORY_SCOPE_AGENT);
    } else {
        if (tid == 0) {
            while (__hip_atomic_load(&flag[t], __ATOMIC_ACQUIRE, __HIP_MEMORY_SCOPE_AGENT) == 0)
                __builtin_amdgcn_s_sleep(16);
        }
        __syncthreads();
        __threadfence();         // invalidate L1 so scan results are seen
    }

    // ---- query: 64 queries per block (wave wv -> q0 = u*64 + wv*16) ----
    const float M2 = sval[NSEG - 1];
    query_body<MODE>(t, u * 64 + wv * 16, lane, M2, sval,
                     s1_all + (size_t)h * NTOT + (size_t)g * NSEG,
                     out + (size_t)g * NSEG * ostride + h * 64, ostride,
                     AS, SCA, SCS, VAS, CSA, CSS);
}

extern "C" void kernel_launch(void* const* d_in, const int* in_sizes, int n_in,
                              void* d_out, int out_size, void* d_ws, size_t ws_size,
                              hipStream_t stream) {
    const float* h_states = (const float*)d_in[0];
    const float* W_heads = (const float*)d_in[1];
    const float* a_heads = (const float*)d_in[2];
    const float* W_out = (const float*)d_in[3];
    const float* a_out = (const float*)d_in[4];
    float* w = (float*)d_ws;
    float* hh = w + OFF_HH;
    float* xc = w + OFF_XC;
    float* hc = w + OFF_HH;              // reuse: hh dead after fused1
    float* s1h = w + OFF_S1H;
    float* s2h = w + OFF_S2H;
    float* s1o = w + OFF_S1O;
    float* s2o = w + OFF_S2O;
    float* g_sval = w + OFF_SVAL;
    float* g_wN = w + OFF_WN;
    int* g_sidx = (int*)(w + OFF_SIDX);
    float* VAS = w + OFF_VAS;
    float* CSA = w + OFF_CSA;
    float* CSS = w + OFF_CSS;
    float* SCA = w + OFF_SCA;
    float* SCS = w + OFF_SCS;
    float* AS = w + OFF_AS;
    float* TAS = w + OFF_TAS;
    float* TSA = w + OFF_TSA;
    float* TSS = w + OFF_TSS;
    int* cntb = (int*)(w + OFF_CNT);
    int* cnt1 = cntb, *flag1 = cntb + 128;
    int* cnt2 = cntb + 256, *flag2 = cntb + 384;
    float* outp = (float*)d_out;

    gemm1_k<<<dim3(256, 4), 256, 0, stream>>>(h_states, W_heads, a_heads, hh, s1h, s2h, cntb);
    sort_k<<<32, 1024, 0, stream>>>(s2h, 4, g_sval, g_sidx, g_wN);
    fused_k<0><<<1024, 256, 0, stream>>>(hh, 4, 32, g_sidx, g_wN, AS, SCA, SCS,
                                         TAS, TSA, TSS, VAS, CSA, CSS,
                                         s1h, xc, 256, g_sval, cnt1, flag1);
    gemm2_k<<<512, 256, 0, stream>>>(xc, W_out, a_out, hc, s1o, s2o, cntb + 256);
    sort_k<<<8, 1024, 0, stream>>>(s2o, 1, g_sval, g_sidx, g_wN);
    fused_k<1><<<256, 256, 0, stream>>>(hc, 1, 8, g_sidx, g_wN, AS, SCA, SCS,
                                        TAS, TSA, TSS, VAS, CSA, CSS,
                                        s1o, outp, 64, g_sval, cnt2, flag2);
}

// Round 7
// 238.118 us; speedup vs baseline: 2.5810x; 2.5810x over previous
//
#include <hip/hip_runtime.h>
#include <math.h>

#define NTOT 16384
#define NSEG 2048
#define NCH 512            // chunks per task (chunk = 4 positions)

// ws float offsets
#define OFF_HH   0ull        // hh [4][8][2048][64] = 4194304 (hc [8][2048][64] reuses)
#define OFF_XC   4194304ull  // xc [16384][256]
#define OFF_S1H  8388608ull
#define OFF_S2H  8454144ull
#define OFF_S1O  8519680ull
#define OFF_S2O  8536064ull
#define OFF_SVAL 8552448ull
#define OFF_WN   8617984ull
#define OFF_SIDX 8683520ull  // 32*2048 ints
#define OFF_TAS  8749056ull  // 32*512*128 chunk totals (A|S)  -> 10846208
#define OFF_TSA  10846208ull // 32*512 scalar chunk totals (A)
#define OFF_TSS  10862592ull // 32*512 scalar chunk totals (S)
#define OFF_VAS  10878976ull // 32*513*128 scanned chunk rows  -> 12980224
#define OFF_CSA  12980224ull // 32*513 scanned scalar (A prefix; [512]=total)
#define OFF_CSS  12996640ull // 32*513 scanned scalar (S suffix)
                             // end 13013056 floats = 52.1 MB

__device__ inline unsigned long long pack_key(float v, int idx) {
    unsigned u = __float_as_uint(v);
    u = (u & 0x80000000u) ? ~u : (u | 0x80000000u);
    return ((unsigned long long)u << 32) | (unsigned)idx;
}
__device__ inline float unpack_key(unsigned long long k) {
    unsigned u = (unsigned)(k >> 32);
    u = (u & 0x80000000u) ? (u ^ 0x80000000u) : ~u;
    return __uint_as_float(u);
}
__device__ inline unsigned long long shfl_xor_u64(unsigned long long x, int mask) {
    unsigned lo = (unsigned)x, hi = (unsigned)(x >> 32);
    lo = (unsigned)__shfl_xor((int)lo, mask, 64);
    hi = (unsigned)__shfl_xor((int)hi, mask, 64);
    return ((unsigned long long)hi << 32) | lo;
}

// ---------------- GEMM 1 + fused s1/s2 projection; hh head-major [h][g][n][64] ----------------
__global__ __launch_bounds__(256) void gemm1_k(const float* __restrict__ X,
                                               const float* __restrict__ Wh,
                                               const float* __restrict__ aH,
                                               float* __restrict__ hh,
                                               float* __restrict__ s1h,
                                               float* __restrict__ s2h) {
    __shared__ float As[64][68];
    __shared__ float Bs[64][68];
    const int tid = threadIdx.x;
    const int bm = blockIdx.x, h = blockIdx.y;
    const int c0 = tid & 63, r0 = tid >> 6;
#pragma unroll
    for (int r = 0; r < 16; ++r) {
        int row = r0 + r * 4;
        As[c0][row] = X[(size_t)(bm * 64 + row) * 64 + c0];
        Bs[row][c0] = Wh[h * 4096 + row * 64 + c0];
    }
    __syncthreads();
    const int tx = tid & 15, ty = tid >> 4;
    const int m0 = ty * 4, n0 = tx * 4;
    float acc[4][4] = {};
#pragma unroll
    for (int kk = 0; kk < 64; ++kk) {
        float4 a = *(const float4*)&As[kk][m0];
        float4 b = *(const float4*)&Bs[kk][n0];
        acc[0][0] += a.x * b.x; acc[0][1] += a.x * b.y; acc[0][2] += a.x * b.z; acc[0][3] += a.x * b.w;
        acc[1][0] += a.y * b.x; acc[1][1] += a.y * b.y; acc[1][2] += a.y * b.z; acc[1][3] += a.y * b.w;
        acc[2][0] += a.z * b.x; acc[2][1] += a.z * b.y; acc[2][2] += a.z * b.z; acc[2][3] += a.z * b.w;
        acc[3][0] += a.w * b.x; acc[3][1] += a.w * b.y; acc[3][2] += a.w * b.z; acc[3][3] += a.w * b.w;
    }
    const int g = bm >> 5;
    const int nb = (bm * 64) & 2047;
#pragma unroll
    for (int i = 0; i < 4; ++i) {
        float4 v = make_float4(acc[i][0], acc[i][1], acc[i][2], acc[i][3]);
        *(float4*)&hh[(((size_t)h * 8 + g) * NSEG + nb + m0 + i) * 64 + n0] = v;
    }
#pragma unroll
    for (int i = 0; i < 4; ++i) {
        float p1 = 0.f, p2 = 0.f;
#pragma unroll
        for (int jj = 0; jj < 4; ++jj) {
            p1 += acc[i][jj] * aH[h * 128 + n0 + jj];
            p2 += acc[i][jj] * aH[h * 128 + 64 + n0 + jj];
        }
#pragma unroll
        for (int off = 8; off; off >>= 1) {
            p1 += __shfl_xor(p1, off, 16);
            p2 += __shfl_xor(p2, off, 16);
        }
        if (tx == 0) {
            s1h[h * NTOT + bm * 64 + m0 + i] = p1;
            s2h[h * NTOT + bm * 64 + m0 + i] = p2;
        }
    }
}

// ---------------- GEMM 2 (BM=32, 512 blocks) + fused s1/s2 projection ----------------
__global__ __launch_bounds__(256) void gemm2_k(const float* __restrict__ XC,
                                               const float* __restrict__ Wo,
                                               const float* __restrict__ aO,
                                               float* __restrict__ hc,
                                               float* __restrict__ s1o,
                                               float* __restrict__ s2o) {
    __shared__ float As[64][34];
    __shared__ float Bs[64][68];
    const int tid = threadIdx.x;
    const int bm = blockIdx.x;
    const int c0 = tid & 63, r0 = tid >> 6;
    const int tx = tid & 15, ty = tid >> 4;
    const int m0 = ty * 2, n0 = tx * 4;
    float acc[2][4] = {};
    for (int kt = 0; kt < 4; ++kt) {
#pragma unroll
        for (int r = 0; r < 8; ++r) {
            int row = r0 + r * 4;
            As[c0][row] = XC[(size_t)(bm * 32 + row) * 256 + kt * 64 + c0];
        }
#pragma unroll
        for (int r = 0; r < 16; ++r) {
            int row = r0 + r * 4;
            Bs[row][c0] = Wo[(kt * 64 + row) * 64 + c0];
        }
        __syncthreads();
#pragma unroll
        for (int kk = 0; kk < 64; ++kk) {
            float2 a = *(const float2*)&As[kk][m0];
            float4 b = *(const float4*)&Bs[kk][n0];
            acc[0][0] += a.x * b.x; acc[0][1] += a.x * b.y; acc[0][2] += a.x * b.z; acc[0][3] += a.x * b.w;
            acc[1][0] += a.y * b.x; acc[1][1] += a.y * b.y; acc[1][2] += a.y * b.z; acc[1][3] += a.y * b.w;
        }
        __syncthreads();
    }
#pragma unroll
    for (int i = 0; i < 2; ++i) {
        float4 v = make_float4(acc[i][0], acc[i][1], acc[i][2], acc[i][3]);
        *(float4*)&hc[(size_t)(bm * 32 + m0 + i) * 64 + n0] = v;
    }
#pragma unroll
    for (int i = 0; i < 2; ++i) {
        float p1 = 0.f, p2 = 0.f;
#pragma unroll
        for (int jj = 0; jj < 4; ++jj) {
            p1 += acc[i][jj] * aO[n0 + jj];
            p2 += acc[i][jj] * aO[64 + n0 + jj];
        }
#pragma unroll
        for (int off = 8; off; off >>= 1) {
            p1 += __shfl_xor(p1, off, 16);
            p2 += __shfl_xor(p2, off, 16);
        }
        if (tx == 0) {
            s1o[bm * 32 + m0 + i] = p1;
            s2o[bm * 32 + m0 + i] = p2;
        }
    }
}

// ---------------- lean bitonic sort: 1 block per task ----------------
__global__ __launch_bounds__(1024) void sort_k(const float* __restrict__ s2_all,
                                               int heads,
                                               float* __restrict__ g_sval,
                                               int* __restrict__ g_sidx,
                                               float* __restrict__ g_wN) {
    __shared__ unsigned long long sA[2][1024];
    __shared__ unsigned long long sB[2][1024];
    __shared__ float sM2;
    const int tid = threadIdx.x, t = blockIdx.x;
    const int g = t / heads, h = t % heads;
    const float* s2p = s2_all + (size_t)h * NTOT + (size_t)g * NSEG;

    unsigned long long a0 = pack_key(s2p[tid], tid);
    unsigned long long a1 = pack_key(s2p[tid + 1024], tid + 1024);
    int p = 0;
    for (int k = 2; k <= 2048; k <<= 1) {
        const bool up0 = (tid & k) == 0;
        const bool up1 = (((tid + 1024) & k) == 0);
        for (int j = k >> 1; j > 0; j >>= 1) {
            if (j >= 1024) {
                unsigned long long lo = a0 < a1 ? a0 : a1;
                unsigned long long hi = a0 < a1 ? a1 : a0;
                a0 = up0 ? lo : hi;
                a1 = up0 ? hi : lo;
            } else if (j >= 64) {
                sA[p][tid] = a0; sB[p][tid] = a1;
                __syncthreads();
                unsigned long long q0 = sA[p][tid ^ j], q1 = sB[p][tid ^ j];
                bool lower = (tid & j) == 0;
                a0 = ((a0 < q0) == (lower == up0)) ? a0 : q0;
                a1 = ((a1 < q1) == (lower == up1)) ? a1 : q1;
                p ^= 1;
            } else {
                unsigned long long q0 = shfl_xor_u64(a0, j);
                unsigned long long q1 = shfl_xor_u64(a1, j);
                bool lower = (tid & j) == 0;
                a0 = ((a0 < q0) == (lower == up0)) ? a0 : q0;
                a1 = ((a1 < q1) == (lower == up1)) ? a1 : q1;
            }
        }
    }
    float v0 = unpack_key(a0), v1 = unpack_key(a1);
    if (tid == 1023) sM2 = v1;
    __syncthreads();
    const float M2 = sM2;
    int i0 = (int)(unsigned)(a0 & 0xffffffffu);
    int i1 = (int)(unsigned)(a1 & 0xffffffffu);
    float w0 = __expf(0.2f * (v0 - M2));
    float w1 = __expf(0.2f * (v1 - M2));
    size_t o = (size_t)t * NSEG;
    g_sval[o + tid] = v0; g_sval[o + tid + 1024] = v1;
    g_sidx[o + tid] = i0; g_sidx[o + tid + 1024] = i1;
    g_wN[o + tid] = w0;   g_wN[o + tid + 1024] = w1;
}

// ---------------- chunk-total build (chunk=4): wave wv -> 4 chunks; no per-position table ----------------
__global__ __launch_bounds__(256) void tabw_k(const float* __restrict__ V,
                                              int heads, int ntask,
                                              const int* __restrict__ g_sidx,
                                              const float* __restrict__ g_wN,
                                              float* __restrict__ TAS,
                                              float* __restrict__ TSAa, float* __restrict__ TSSa) {
    const int L = blockIdx.x + (int)(gridDim.x * blockIdx.y);
    const int xcd = L & 7, slot = L >> 3;
    const int tpx = ntask >> 3;
    const int t = xcd * tpx + (slot >> 5);
    const int u = slot & 31;
    const int wv = threadIdx.x >> 6, lane = threadIdx.x & 63;
    const int g = t / heads, h = t % heads;
    const int seg = h * (ntask / heads) + g;
    const float* Vp = V + (size_t)seg * NSEG * 64;
#pragma unroll
    for (int cc = 0; cc < 4; ++cc) {
        const int c = u * 16 + wv * 4 + cc;       // chunk id 0..511
        const int base = c << 2;
        const int4 si = *(const int4*)&g_sidx[(size_t)t * NSEG + base];
        const float4 w4 = *(const float4*)&g_wN[(size_t)t * NSEG + base];
        float v0 = Vp[(size_t)si.x * 64 + lane];
        float v1 = Vp[(size_t)si.y * 64 + lane];
        float v2 = Vp[(size_t)si.z * 64 + lane];
        float v3 = Vp[(size_t)si.w * 64 + lane];
        float w0 = w4.x, w1 = w4.y, w2 = w4.z, w3 = w4.w;
        float p0 = w0 * w0 * w0 * w0 * w0, p1 = w1 * w1 * w1 * w1 * w1;
        float p2 = w2 * w2 * w2 * w2 * w2, p3 = w3 * w3 * w3 * w3 * w3;
        float ta = w0 * v0 + w1 * v1 + w2 * v2 + w3 * v3;
        float ts = p0 * v0 + p1 * v1 + p2 * v2 + p3 * v3;
        float* row = TAS + ((size_t)t * NCH + c) * 128;
        row[lane] = ta;
        row[64 + lane] = ts;
        if (lane == 0) {
            TSAa[(size_t)t * NCH + c] = w0 + w1 + w2 + w3;
            TSSa[(size_t)t * NCH + c] = p0 + p1 + p2 + p3;
        }
    }
}

// ---------------- per-task scan of 512 chunk totals ----------------
__global__ __launch_bounds__(256) void scan_k(const float* __restrict__ TAS,
                                              const float* __restrict__ TSAa,
                                              const float* __restrict__ TSSa,
                                              float* __restrict__ VAS,
                                              float* __restrict__ CSAa, float* __restrict__ CSSa) {
    const int t = blockIdx.x, tid = threadIdx.x;
    const float* T = TAS + (size_t)t * NCH * 128;
    float* Vo = VAS + (size_t)t * (NCH + 1) * 128;
    if (tid < 64) {                 // A columns: exclusive prefix over chunks
        float run = 0.f;
#pragma unroll 8
        for (int c = 0; c < NCH; ++c) { Vo[(size_t)c * 128 + tid] = run; run += T[(size_t)c * 128 + tid]; }
        Vo[(size_t)NCH * 128 + tid] = run;     // full total (k==2048)
    } else if (tid < 128) {         // S columns: exclusive suffix over chunks
        float run = 0.f;
#pragma unroll 8
        for (int c = NCH - 1; c >= 0; --c) { Vo[(size_t)c * 128 + tid] = run; run += T[(size_t)c * 128 + tid]; }
    } else if (tid == 128) {        // A scalar
        float run = 0.f;
        for (int c = 0; c < NCH; ++c) { CSAa[t * (NCH + 1) + c] = run; run += TSAa[(size_t)t * NCH + c]; }
        CSAa[t * (NCH + 1) + NCH] = run;
    } else if (tid == 129) {        // S scalar
        float run = 0.f;
        for (int c = NCH - 1; c >= 0; --c) { CSSa[t * (NCH + 1) + c] = run; run += TSSa[(size_t)t * NCH + c]; }
    }
}

// ---------------- query: binary search + chunk row + 4-row in-chunk correction ----------------
template <int MODE>  // 0: ELU -> xc ; 1: ELU + log_softmax -> out
__global__ __launch_bounds__(256) void query_k(const float* __restrict__ s1_all,
                                               float* __restrict__ out,
                                               int heads, int ntask, int ostride,
                                               const float* __restrict__ g_sval,
                                               const int* __restrict__ g_sidx,
                                               const float* __restrict__ g_wN,
                                               const float* __restrict__ V,
                                               const float* __restrict__ VAS,
                                               const float* __restrict__ CSAa,
                                               const float* __restrict__ CSSa) {
    __shared__ float sval[NSEG];
    const int tid = threadIdx.x;
    const int L = blockIdx.x + (int)(gridDim.x * blockIdx.y);
    const int xcd = L & 7, slot = L >> 3;
    const int tpx = ntask >> 3;
    const int t = xcd * tpx + (slot >> 5);
    const int u = slot & 31;
    const int g = t / heads, h = t % heads;
    const int seg = h * (ntask / heads) + g;
    const float* Vp = V + (size_t)seg * NSEG * 64;
    const float4* sv4 = (const float4*)(g_sval + (size_t)t * NSEG);
    for (int i = tid; i < NSEG / 4; i += 256) ((float4*)sval)[i] = sv4[i];
    __syncthreads();
    const float M2 = sval[NSEG - 1];
    const int lane = tid & 63, wv = tid >> 6;
    const int q0 = u * 64 + wv * 16;
    const float* s1p = s1_all + (size_t)h * NTOT + (size_t)g * NSEG;
    float* outp = out + (size_t)g * NSEG * ostride + h * 64;
    const float* VASp = VAS + (size_t)t * (NCH + 1) * 128;
    const float* csA = CSAa + (size_t)t * (NCH + 1);
    const float* csS = CSSa + (size_t)t * (NCH + 1);
    int myq = q0 + (lane & 15);
    float s1v = s1p[myq];
    float th = -s1v;
    int lo = 0, hi = NSEG;
    while (lo < hi) { int mid = (lo + hi) >> 1; if (sval[mid] <= th) lo = mid + 1; else hi = mid; }
#pragma unroll 4
    for (int j = 0; j < 16; ++j) {
        int k = __shfl(lo, j, 64);
        float s1q = __shfl(s1v, j, 64);
        float accA, scaA, accS, scaS;
        if (k < NSEG) {
            const int c = k >> 2;
            const int base = c << 2;
            const float* row = VASp + (size_t)c * 128;
            accA = row[lane]; accS = row[64 + lane];
            scaA = csA[c];    scaS = csS[c];
            const int4 si = *(const int4*)&g_sidx[(size_t)t * NSEG + base];
            const float4 w4 = *(const float4*)&g_wN[(size_t)t * NSEG + base];
#pragma unroll
            for (int jj = 0; jj < 4; ++jj) {
                int idx = (jj == 0) ? si.x : (jj == 1) ? si.y : (jj == 2) ? si.z : si.w;
                float wn = (jj == 0) ? w4.x : (jj == 1) ? w4.y : (jj == 2) ? w4.z : w4.w;
                float v = Vp[(size_t)idx * 64 + lane];
                float wp = wn * wn * wn * wn * wn;
                if (base + jj < k) { accA += wn * v; scaA += wn; }
                else               { accS += wp * v; scaS += wp; }
            }
        } else {
            accA = VASp[(size_t)NCH * 128 + lane]; scaA = csA[NCH];
            accS = 0.f; scaS = 0.f;
        }
        float cc = __expf(-0.8f * fmaxf(s1q + M2, 0.f));
        float o = (accS + cc * accA) / (scaS + cc * scaA);
        o = o > 0.f ? o : expm1f(o);  // ELU
        int q = q0 + j;
        if (MODE == 0) {
            outp[(size_t)q * ostride + lane] = o;
        } else {
            float m = o;
#pragma unroll
            for (int off = 32; off; off >>= 1) m = fmaxf(m, __shfl_xor(m, off, 64));
            float e = __expf(o - m);
#pragma unroll
            for (int off = 32; off; off >>= 1) e += __shfl_xor(e, off, 64);
            outp[(size_t)q * ostride + lane] = o - m - __logf(e);
        }
    }
}

extern "C" void kernel_launch(void* const* d_in, const int* in_sizes, int n_in,
                              void* d_out, int out_size, void* d_ws, size_t ws_size,
                              hipStream_t stream) {
    const float* h_states = (const float*)d_in[0];
    const float* W_heads = (const float*)d_in[1];
    const float* a_heads = (const float*)d_in[2];
    const float* W_out = (const float*)d_in[3];
    const float* a_out = (const float*)d_in[4];
    float* w = (float*)d_ws;
    float* hh = w + OFF_HH;
    float* xc = w + OFF_XC;
    float* hc = w + OFF_HH;              // reuse: hh dead after query1
    float* s1h = w + OFF_S1H;
    float* s2h = w + OFF_S2H;
    float* s1o = w + OFF_S1O;
    float* s2o = w + OFF_S2O;
    float* g_sval = w + OFF_SVAL;
    float* g_wN = w + OFF_WN;
    int* g_sidx = (int*)(w + OFF_SIDX);
    float* TAS = w + OFF_TAS;
    float* TSAa = w + OFF_TSA;
    float* TSSa = w + OFF_TSS;
    float* VAS = w + OFF_VAS;
    float* CSAa = w + OFF_CSA;
    float* CSSa = w + OFF_CSS;
    float* outp = (float*)d_out;

    gemm1_k<<<dim3(256, 4), 256, 0, stream>>>(h_states, W_heads, a_heads, hh, s1h, s2h);
    sort_k<<<32, 1024, 0, stream>>>(s2h, 4, g_sval, g_sidx, g_wN);
    tabw_k<<<dim3(32, 32), 256, 0, stream>>>(hh, 4, 32, g_sidx, g_wN, TAS, TSAa, TSSa);
    scan_k<<<32, 256, 0, stream>>>(TAS, TSAa, TSSa, VAS, CSAa, CSSa);
    query_k<0><<<dim3(32, 32), 256, 0, stream>>>(s1h, xc, 4, 32, 256, g_sval, g_sidx, g_wN,
                                                 hh, VAS, CSAa, CSSa);
    gemm2_k<<<512, 256, 0, stream>>>(xc, W_out, a_out, hc, s1o, s2o);
    sort_k<<<8, 1024, 0, stream>>>(s2o, 1, g_sval, g_sidx, g_wN);
    tabw_k<<<dim3(32, 8), 256, 0, stream>>>(hc, 1, 8, g_sidx, g_wN, TAS, TSAa, TSSa);
    scan_k<<<8, 256, 0, stream>>>(TAS, TSAa, TSSa, VAS, CSAa, CSSa);
    query_k<1><<<dim3(32, 8), 256, 0, stream>>>(s1o, outp, 1, 8, 64, g_sval, g_sidx, g_wN,
                                                hc, VAS, CSAa, CSSa);
}

// Round 8
// 182.392 us; speedup vs baseline: 3.3696x; 1.3055x over previous
//
#include <hip/hip_runtime.h>
#include <math.h>

#define NTOT 16384
#define NSEG 2048

// ws float offsets
#define OFF_HH   0ull         // hh [4][8][2048][64] = 4194304 (hc [8][2048][64] reuses)
#define OFF_XC   4194304ull   // xc [16384][256] (exclusive now)
#define OFF_S1H  8388608ull
#define OFF_S2H  8454144ull
#define OFF_S1O  8519680ull
#define OFF_S2O  8536064ull
#define OFF_SVAL 8552448ull
#define OFF_WN   8617984ull
#define OFF_SIDX 8683520ull   // 32*2048 ints
#define OFF_SCA  9285696ull   // 32*2048 per-pos scalar (A)
#define OFF_SCS  9351232ull   // 32*2048 per-pos scalar (S)
#define OFF_AS   9416768ull   // 32*2048*128 per-pos vectors (A|S) -> 17805376
#define OFF_TAS  17805376ull  // 32*128*128 chunk totals (A|S)    -> 18329664
#define OFF_TSA  18329664ull  // 32*128 scalar chunk totals (A)
#define OFF_TSS  18333760ull  // 32*128 scalar chunk totals (S)   -> end 18337856 (73.4 MB)

__device__ inline unsigned long long pack_key(float v, int idx) {
    unsigned u = __float_as_uint(v);
    u = (u & 0x80000000u) ? ~u : (u | 0x80000000u);
    return ((unsigned long long)u << 32) | (unsigned)idx;
}
__device__ inline float unpack_key(unsigned long long k) {
    unsigned u = (unsigned)(k >> 32);
    u = (u & 0x80000000u) ? (u ^ 0x80000000u) : ~u;
    return __uint_as_float(u);
}
__device__ inline unsigned long long shfl_xor_u64(unsigned long long x, int mask) {
    unsigned lo = (unsigned)x, hi = (unsigned)(x >> 32);
    lo = (unsigned)__shfl_xor((int)lo, mask, 64);
    hi = (unsigned)__shfl_xor((int)hi, mask, 64);
    return ((unsigned long long)hi << 32) | lo;
}

// ---------------- GEMM 1 + fused s1/s2 projection; hh head-major [h][g][n][64] ----------------
__global__ __launch_bounds__(256) void gemm1_k(const float* __restrict__ X,
                                               const float* __restrict__ Wh,
                                               const float* __restrict__ aH,
                                               float* __restrict__ hh,
                                               float* __restrict__ s1h,
                                               float* __restrict__ s2h) {
    __shared__ float As[64][68];
    __shared__ float Bs[64][68];
    const int tid = threadIdx.x;
    const int bm = blockIdx.x, h = blockIdx.y;
    const int c0 = tid & 63, r0 = tid >> 6;
#pragma unroll
    for (int r = 0; r < 16; ++r) {
        int row = r0 + r * 4;
        As[c0][row] = X[(size_t)(bm * 64 + row) * 64 + c0];
        Bs[row][c0] = Wh[h * 4096 + row * 64 + c0];
    }
    __syncthreads();
    const int tx = tid & 15, ty = tid >> 4;
    const int m0 = ty * 4, n0 = tx * 4;
    float acc[4][4] = {};
#pragma unroll
    for (int kk = 0; kk < 64; ++kk) {
        float4 a = *(const float4*)&As[kk][m0];
        float4 b = *(const float4*)&Bs[kk][n0];
        acc[0][0] += a.x * b.x; acc[0][1] += a.x * b.y; acc[0][2] += a.x * b.z; acc[0][3] += a.x * b.w;
        acc[1][0] += a.y * b.x; acc[1][1] += a.y * b.y; acc[1][2] += a.y * b.z; acc[1][3] += a.y * b.w;
        acc[2][0] += a.z * b.x; acc[2][1] += a.z * b.y; acc[2][2] += a.z * b.z; acc[2][3] += a.z * b.w;
        acc[3][0] += a.w * b.x; acc[3][1] += a.w * b.y; acc[3][2] += a.w * b.z; acc[3][3] += a.w * b.w;
    }
    const int g = bm >> 5;
    const int nb = (bm * 64) & 2047;
#pragma unroll
    for (int i = 0; i < 4; ++i) {
        float4 v = make_float4(acc[i][0], acc[i][1], acc[i][2], acc[i][3]);
        *(float4*)&hh[(((size_t)h * 8 + g) * NSEG + nb + m0 + i) * 64 + n0] = v;
    }
#pragma unroll
    for (int i = 0; i < 4; ++i) {
        float p1 = 0.f, p2 = 0.f;
#pragma unroll
        for (int jj = 0; jj < 4; ++jj) {
            p1 += acc[i][jj] * aH[h * 128 + n0 + jj];
            p2 += acc[i][jj] * aH[h * 128 + 64 + n0 + jj];
        }
#pragma unroll
        for (int off = 8; off; off >>= 1) {
            p1 += __shfl_xor(p1, off, 16);
            p2 += __shfl_xor(p2, off, 16);
        }
        if (tx == 0) {
            s1h[h * NTOT + bm * 64 + m0 + i] = p1;
            s2h[h * NTOT + bm * 64 + m0 + i] = p2;
        }
    }
}

// ---------------- GEMM 2 (BM=32, 512 blocks) + fused s1/s2 projection ----------------
__global__ __launch_bounds__(256) void gemm2_k(const float* __restrict__ XC,
                                               const float* __restrict__ Wo,
                                               const float* __restrict__ aO,
                                               float* __restrict__ hc,
                                               float* __restrict__ s1o,
                                               float* __restrict__ s2o) {
    __shared__ float As[64][34];
    __shared__ float Bs[64][68];
    const int tid = threadIdx.x;
    const int bm = blockIdx.x;
    const int c0 = tid & 63, r0 = tid >> 6;
    const int tx = tid & 15, ty = tid >> 4;
    const int m0 = ty * 2, n0 = tx * 4;
    float acc[2][4] = {};
    for (int kt = 0; kt < 4; ++kt) {
#pragma unroll
        for (int r = 0; r < 8; ++r) {
            int row = r0 + r * 4;
            As[c0][row] = XC[(size_t)(bm * 32 + row) * 256 + kt * 64 + c0];
        }
#pragma unroll
        for (int r = 0; r < 16; ++r) {
            int row = r0 + r * 4;
            Bs[row][c0] = Wo[(kt * 64 + row) * 64 + c0];
        }
        __syncthreads();
#pragma unroll
        for (int kk = 0; kk < 64; ++kk) {
            float2 a = *(const float2*)&As[kk][m0];
            float4 b = *(const float4*)&Bs[kk][n0];
            acc[0][0] += a.x * b.x; acc[0][1] += a.x * b.y; acc[0][2] += a.x * b.z; acc[0][3] += a.x * b.w;
            acc[1][0] += a.y * b.x; acc[1][1] += a.y * b.y; acc[1][2] += a.y * b.z; acc[1][3] += a.y * b.w;
        }
        __syncthreads();
    }
#pragma unroll
    for (int i = 0; i < 2; ++i) {
        float4 v = make_float4(acc[i][0], acc[i][1], acc[i][2], acc[i][3]);
        *(float4*)&hc[(size_t)(bm * 32 + m0 + i) * 64 + n0] = v;
    }
#pragma unroll
    for (int i = 0; i < 2; ++i) {
        float p1 = 0.f, p2 = 0.f;
#pragma unroll
        for (int jj = 0; jj < 4; ++jj) {
            p1 += acc[i][jj] * aO[n0 + jj];
            p2 += acc[i][jj] * aO[64 + n0 + jj];
        }
#pragma unroll
        for (int off = 8; off; off >>= 1) {
            p1 += __shfl_xor(p1, off, 16);
            p2 += __shfl_xor(p2, off, 16);
        }
        if (tx == 0) {
            s1o[bm * 32 + m0 + i] = p1;
            s2o[bm * 32 + m0 + i] = p2;
        }
    }
}

// ---------------- lean bitonic sort: 1 block per task ----------------
__global__ __launch_bounds__(1024) void sort_k(const float* __restrict__ s2_all,
                                               int heads,
                                               float* __restrict__ g_sval,
                                               int* __restrict__ g_sidx,
                                               float* __restrict__ g_wN) {
    __shared__ unsigned long long sA[2][1024];
    __shared__ unsigned long long sB[2][1024];
    __shared__ float sM2;
    const int tid = threadIdx.x, t = blockIdx.x;
    const int g = t / heads, h = t % heads;
    const float* s2p = s2_all + (size_t)h * NTOT + (size_t)g * NSEG;

    unsigned long long a0 = pack_key(s2p[tid], tid);
    unsigned long long a1 = pack_key(s2p[tid + 1024], tid + 1024);
    int p = 0;
    for (int k = 2; k <= 2048; k <<= 1) {
        const bool up0 = (tid & k) == 0;
        const bool up1 = (((tid + 1024) & k) == 0);
        for (int j = k >> 1; j > 0; j >>= 1) {
            if (j >= 1024) {
                unsigned long long lo = a0 < a1 ? a0 : a1;
                unsigned long long hi = a0 < a1 ? a1 : a0;
                a0 = up0 ? lo : hi;
                a1 = up0 ? hi : lo;
            } else if (j >= 64) {
                sA[p][tid] = a0; sB[p][tid] = a1;
                __syncthreads();
                unsigned long long q0 = sA[p][tid ^ j], q1 = sB[p][tid ^ j];
                bool lower = (tid & j) == 0;
                a0 = ((a0 < q0) == (lower == up0)) ? a0 : q0;
                a1 = ((a1 < q1) == (lower == up1)) ? a1 : q1;
                p ^= 1;
            } else {
                unsigned long long q0 = shfl_xor_u64(a0, j);
                unsigned long long q1 = shfl_xor_u64(a1, j);
                bool lower = (tid & j) == 0;
                a0 = ((a0 < q0) == (lower == up0)) ? a0 : q0;
                a1 = ((a1 < q1) == (lower == up1)) ? a1 : q1;
            }
        }
    }
    float v0 = unpack_key(a0), v1 = unpack_key(a1);
    if (tid == 1023) sM2 = v1;
    __syncthreads();
    const float M2 = sM2;
    int i0 = (int)(unsigned)(a0 & 0xffffffffu);
    int i1 = (int)(unsigned)(a1 & 0xffffffffu);
    float w0 = __expf(0.2f * (v0 - M2));
    float w1 = __expf(0.2f * (v1 - M2));
    size_t o = (size_t)t * NSEG;
    g_sval[o + tid] = v0; g_sval[o + tid + 1024] = v1;
    g_sidx[o + tid] = i0; g_sidx[o + tid + 1024] = i1;
    g_wN[o + tid] = w0;   g_wN[o + tid + 1024] = w1;
}

// ---------------- wide table build: aligned AS rows + scalar arrays; XCD-clustered tasks ----------------
__global__ __launch_bounds__(256) void tabw_k(const float* __restrict__ V,
                                              int heads, int ntask,
                                              const int* __restrict__ g_sidx,
                                              const float* __restrict__ g_wN,
                                              float* __restrict__ AS,
                                              float* __restrict__ SCA, float* __restrict__ SCS,
                                              float* __restrict__ TAS,
                                              float* __restrict__ TSA, float* __restrict__ TSS) {
    const int L = blockIdx.x + (int)(gridDim.x * blockIdx.y);
    const int xcd = L & 7, slot = L >> 3;
    const int tpx = ntask >> 3;                    // tasks per XCD
    const int t = xcd * tpx + (slot >> 5);
    const int u = slot & 31;
    const int wv = threadIdx.x >> 6, lane = threadIdx.x & 63;
    const int c = u * 4 + wv, base = c * 16;
    const int g = t / heads, h = t % heads;
    const int seg = h * (ntask / heads) + g;       // V segment [seg][2048][64]
    const float* Vp = V + (size_t)seg * NSEG * 64;
    const int* sidx = g_sidx + (size_t)t * NSEG + base;
    const float* wnp = g_wN + (size_t)t * NSEG + base;
    float wn[16], vv[16];
#pragma unroll
    for (int j = 0; j < 16; ++j) wn[j] = wnp[j];
#pragma unroll
    for (int j = 0; j < 16; ++j) vv[j] = Vp[(size_t)sidx[j] * 64 + lane];
    float* ASp = AS + (size_t)t * NSEG * 128;
    // exclusive within-chunk prefix (A half of row)
    float accA = 0.f, scaA = 0.f;
#pragma unroll
    for (int j = 0; j < 16; ++j) {
        size_t pos = base + j;
        ASp[pos * 128 + lane] = accA;
        if (lane == 0) SCA[(size_t)t * NSEG + pos] = scaA;
        accA += wn[j] * vv[j]; scaA += wn[j];
    }
    TAS[((size_t)t * 128 + c) * 128 + lane] = accA;
    if (lane == 0) TSA[t * 128 + c] = scaA;
    // inclusive within-chunk suffix (S half of row)
    float accS = 0.f, scaS = 0.f;
#pragma unroll
    for (int j = 15; j >= 0; --j) {
        float w = wn[j], w2 = w * w, wp = w2 * w2 * w;
        accS += wp * vv[j]; scaS += wp;
        size_t pos = base + j;
        ASp[pos * 128 + 64 + lane] = accS;
        if (lane == 0) SCS[(size_t)t * NSEG + pos] = scaS;
    }
    TAS[((size_t)t * 128 + c) * 128 + 64 + lane] = accS;
    if (lane == 0) TSS[t * 128 + c] = scaS;
}

// ---------------- query with fused in-LDS chunk scan: 1024 thr, 256 q/block ----------------
template <int MODE>  // 0: ELU -> xc ; 1: ELU + log_softmax -> out
__global__ __launch_bounds__(1024) void query_k(const float* __restrict__ s1_all,
                                                float* __restrict__ out,
                                                int heads, int ntask, int ostride,
                                                const float* __restrict__ g_sval,
                                                const float* __restrict__ AS,
                                                const float* __restrict__ SCA, const float* __restrict__ SCS,
                                                const float* __restrict__ TAS,
                                                const float* __restrict__ TSA, const float* __restrict__ TSS) {
    __shared__ float sval[NSEG];        // 8 KB
    __shared__ float Ts[128 * 128];     // 64 KB: chunk rows, scanned in place
    __shared__ float totA[64];          // A totals (k==2048 case)
    __shared__ float csa[132];          // scanned scalar A (csa[128] = total)
    __shared__ float css[132];          // scanned scalar S
    const int tid = threadIdx.x;
    const int L = blockIdx.x;
    const int xcd = L & 7, slot = L >> 3;
    const int tpx = ntask >> 3;
    const int t = xcd * tpx + (slot >> 3);      // 8 blocks per task
    const int u = slot & 7;
    const int g = t / heads, h = t % heads;
    // stage sval + TAS slice
    const float4* sv4 = (const float4*)(g_sval + (size_t)t * NSEG);
    if (tid < 512) ((float4*)sval)[tid] = sv4[tid];
    const float4* Tg4 = (const float4*)(TAS + (size_t)t * 128 * 128);
    float4* Ts4 = (float4*)Ts;
#pragma unroll
    for (int i = 0; i < 4; ++i) Ts4[tid + i * 1024] = Tg4[tid + i * 1024];
    __syncthreads();
    // in-place exclusive scans over 128 chunks (redundant per block; no fences needed)
    if (tid < 64) {                 // A columns 0..63: exclusive prefix
        float run = 0.f;
        for (int c = 0; c < 128; ++c) { float v = Ts[c * 128 + tid]; Ts[c * 128 + tid] = run; run += v; }
        totA[tid] = run;
    } else if (tid < 128) {         // S columns 64..127: exclusive suffix
        float run = 0.f;
        for (int c = 127; c >= 0; --c) { float v = Ts[c * 128 + tid]; Ts[c * 128 + tid] = run; run += v; }
    } else if (tid == 128) {        // scalar A
        const float* TSAp = TSA + (size_t)t * 128;
        float run = 0.f;
        for (int c = 0; c < 128; ++c) { csa[c] = run; run += TSAp[c]; }
        csa[128] = run;
    } else if (tid == 129) {        // scalar S
        const float* TSSp = TSS + (size_t)t * 128;
        float run = 0.f;
        for (int c = 127; c >= 0; --c) { css[c] = run; run += TSSp[c]; }
    }
    __syncthreads();
    const float M2 = sval[NSEG - 1];
    const int lane = tid & 63, wv = tid >> 6;       // 16 waves
    const int q0 = u * 256 + wv * 16;
    const float* s1p = s1_all + (size_t)h * NTOT + (size_t)g * NSEG;
    float* outp = out + (size_t)g * NSEG * ostride + h * 64;
    const float* ASp = AS + (size_t)t * NSEG * 128;
    const float* scA = SCA + (size_t)t * NSEG;
    const float* scS = SCS + (size_t)t * NSEG;
    int myq = q0 + (lane & 15);
    float s1v = s1p[myq];
    float th = -s1v;
    int lo = 0, hi = NSEG;
    while (lo < hi) { int mid = (lo + hi) >> 1; if (sval[mid] <= th) lo = mid + 1; else hi = mid; }
#pragma unroll 4
    for (int j = 0; j < 16; ++j) {
        int k = __shfl(lo, j, 64);
        float s1q = __shfl(s1v, j, 64);
        float accA, scaA, accS, scaS;
        if (k < NSEG) {
            const int c = k >> 4;
            const float* rowP = ASp + (size_t)k * 128;
            accA = rowP[lane]      + Ts[c * 128 + lane];
            accS = rowP[64 + lane] + Ts[c * 128 + 64 + lane];
            scaA = scA[k] + csa[c];
            scaS = scS[k] + css[c];
        } else {
            accA = totA[lane]; scaA = csa[128];
            accS = 0.f; scaS = 0.f;
        }
        float cc = __expf(-0.8f * fmaxf(s1q + M2, 0.f));
        float o = (accS + cc * accA) / (scaS + cc * scaA);
        o = o > 0.f ? o : expm1f(o);  // ELU
        int q = q0 + j;
        if (MODE == 0) {
            outp[(size_t)q * ostride + lane] = o;
        } else {
            float m = o;
#pragma unroll
            for (int off = 32; off; off >>= 1) m = fmaxf(m, __shfl_xor(m, off, 64));
            float e = __expf(o - m);
#pragma unroll
            for (int off = 32; off; off >>= 1) e += __shfl_xor(e, off, 64);
            outp[(size_t)q * ostride + lane] = o - m - __logf(e);
        }
    }
}

extern "C" void kernel_launch(void* const* d_in, const int* in_sizes, int n_in,
                              void* d_out, int out_size, void* d_ws, size_t ws_size,
                              hipStream_t stream) {
    const float* h_states = (const float*)d_in[0];
    const float* W_heads = (const float*)d_in[1];
    const float* a_heads = (const float*)d_in[2];
    const float* W_out = (const float*)d_in[3];
    const float* a_out = (const float*)d_in[4];
    float* w = (float*)d_ws;
    float* hh = w + OFF_HH;
    float* xc = w + OFF_XC;
    float* hc = w + OFF_HH;              // reuse: hh dead after tabw1
    float* s1h = w + OFF_S1H;
    float* s2h = w + OFF_S2H;
    float* s1o = w + OFF_S1O;
    float* s2o = w + OFF_S2O;
    float* g_sval = w + OFF_SVAL;
    float* g_wN = w + OFF_WN;
    int* g_sidx = (int*)(w + OFF_SIDX);
    float* SCA = w + OFF_SCA;
    float* SCS = w + OFF_SCS;
    float* AS = w + OFF_AS;
    float* TAS = w + OFF_TAS;            // fresh region — no xc aliasing (query reads while writing xc)
    float* TSA = w + OFF_TSA;
    float* TSS = w + OFF_TSS;
    float* outp = (float*)d_out;

    gemm1_k<<<dim3(256, 4), 256, 0, stream>>>(h_states, W_heads, a_heads, hh, s1h, s2h);
    sort_k<<<32, 1024, 0, stream>>>(s2h, 4, g_sval, g_sidx, g_wN);
    tabw_k<<<dim3(32, 32), 256, 0, stream>>>(hh, 4, 32, g_sidx, g_wN, AS, SCA, SCS, TAS, TSA, TSS);
    query_k<0><<<256, 1024, 0, stream>>>(s1h, xc, 4, 32, 256, g_sval, AS, SCA, SCS, TAS, TSA, TSS);
    gemm2_k<<<512, 256, 0, stream>>>(xc, W_out, a_out, hc, s1o, s2o);
    sort_k<<<8, 1024, 0, stream>>>(s2o, 1, g_sval, g_sidx, g_wN);
    tabw_k<<<dim3(32, 8), 256, 0, stream>>>(hc, 1, 8, g_sidx, g_wN, AS, SCA, SCS, TAS, TSA, TSS);
    query_k<1><<<64, 1024, 0, stream>>>(s1o, outp, 1, 8, 64, g_sval, AS, SCA, SCS, TAS, TSA, TSS);
}

// Round 9
// 180.563 us; speedup vs baseline: 3.4037x; 1.0101x over previous
//
#include <hip/hip_runtime.h>
#include <math.h>

#define NTOT 16384
#define NSEG 2048

// ws float offsets
#define OFF_HH   0ull         // hh [4][8][2048][64] = 4194304 (hc [8][2048][64] reuses)
#define OFF_XC   4194304ull   // xc [16384][256] (exclusive)
#define OFF_S1H  8388608ull
#define OFF_S2H  8454144ull
#define OFF_S1O  8519680ull
#define OFF_S2O  8536064ull
#define OFF_SVAL 8552448ull
#define OFF_WN   8617984ull
#define OFF_SIDX 8683520ull   // 32*2048 ints
#define OFF_SCA  9285696ull   // 32*2048 per-pos scalar (A)
#define OFF_SCS  9351232ull   // 32*2048 per-pos scalar (S)
#define OFF_AS   9416768ull   // 32*2048*128 per-pos vectors (A|S) -> 17805376
#define OFF_TAS  17805376ull  // 32*128*128 chunk totals (A|S)    -> 18329664
#define OFF_TSA  18329664ull  // 32*128 scalar chunk totals (A)
#define OFF_TSS  18333760ull  // 32*128 scalar chunk totals (S)   -> end 18337856 (73.4 MB)

__device__ inline unsigned long long pack_key(float v, int idx) {
    unsigned u = __float_as_uint(v);
    u = (u & 0x80000000u) ? ~u : (u | 0x80000000u);
    return ((unsigned long long)u << 32) | (unsigned)idx;
}
__device__ inline float unpack_key(unsigned long long k) {
    unsigned u = (unsigned)(k >> 32);
    u = (u & 0x80000000u) ? (u ^ 0x80000000u) : ~u;
    return __uint_as_float(u);
}
__device__ inline unsigned long long shfl_xor_u64(unsigned long long x, int mask) {
    unsigned lo = (unsigned)x, hi = (unsigned)(x >> 32);
    lo = (unsigned)__shfl_xor((int)lo, mask, 64);
    hi = (unsigned)__shfl_xor((int)hi, mask, 64);
    return ((unsigned long long)hi << 32) | lo;
}

// ---------------- GEMM 1 + fused s1/s2 projection; hh head-major [h][g][n][64] ----------------
__global__ __launch_bounds__(256) void gemm1_k(const float* __restrict__ X,
                                               const float* __restrict__ Wh,
                                               const float* __restrict__ aH,
                                               float* __restrict__ hh,
                                               float* __restrict__ s1h,
                                               float* __restrict__ s2h) {
    __shared__ float As[64][68];
    __shared__ float Bs[64][68];
    const int tid = threadIdx.x;
    const int bm = blockIdx.x, h = blockIdx.y;
    const int c0 = tid & 63, r0 = tid >> 6;
#pragma unroll
    for (int r = 0; r < 16; ++r) {
        int row = r0 + r * 4;
        As[c0][row] = X[(size_t)(bm * 64 + row) * 64 + c0];
        Bs[row][c0] = Wh[h * 4096 + row * 64 + c0];
    }
    __syncthreads();
    const int tx = tid & 15, ty = tid >> 4;
    const int m0 = ty * 4, n0 = tx * 4;
    float acc[4][4] = {};
#pragma unroll
    for (int kk = 0; kk < 64; ++kk) {
        float4 a = *(const float4*)&As[kk][m0];
        float4 b = *(const float4*)&Bs[kk][n0];
        acc[0][0] += a.x * b.x; acc[0][1] += a.x * b.y; acc[0][2] += a.x * b.z; acc[0][3] += a.x * b.w;
        acc[1][0] += a.y * b.x; acc[1][1] += a.y * b.y; acc[1][2] += a.y * b.z; acc[1][3] += a.y * b.w;
        acc[2][0] += a.z * b.x; acc[2][1] += a.z * b.y; acc[2][2] += a.z * b.z; acc[2][3] += a.z * b.w;
        acc[3][0] += a.w * b.x; acc[3][1] += a.w * b.y; acc[3][2] += a.w * b.z; acc[3][3] += a.w * b.w;
    }
    const int g = bm >> 5;
    const int nb = (bm * 64) & 2047;
#pragma unroll
    for (int i = 0; i < 4; ++i) {
        float4 v = make_float4(acc[i][0], acc[i][1], acc[i][2], acc[i][3]);
        *(float4*)&hh[(((size_t)h * 8 + g) * NSEG + nb + m0 + i) * 64 + n0] = v;
    }
#pragma unroll
    for (int i = 0; i < 4; ++i) {
        float p1 = 0.f, p2 = 0.f;
#pragma unroll
        for (int jj = 0; jj < 4; ++jj) {
            p1 += acc[i][jj] * aH[h * 128 + n0 + jj];
            p2 += acc[i][jj] * aH[h * 128 + 64 + n0 + jj];
        }
#pragma unroll
        for (int off = 8; off; off >>= 1) {
            p1 += __shfl_xor(p1, off, 16);
            p2 += __shfl_xor(p2, off, 16);
        }
        if (tx == 0) {
            s1h[h * NTOT + bm * 64 + m0 + i] = p1;
            s2h[h * NTOT + bm * 64 + m0 + i] = p2;
        }
    }
}

// ---------------- GEMM 2 (BM=32, 512 blocks) + fused s1/s2 projection ----------------
__global__ __launch_bounds__(256) void gemm2_k(const float* __restrict__ XC,
                                               const float* __restrict__ Wo,
                                               const float* __restrict__ aO,
                                               float* __restrict__ hc,
                                               float* __restrict__ s1o,
                                               float* __restrict__ s2o) {
    __shared__ float As[64][34];
    __shared__ float Bs[64][68];
    const int tid = threadIdx.x;
    const int bm = blockIdx.x;
    const int c0 = tid & 63, r0 = tid >> 6;
    const int tx = tid & 15, ty = tid >> 4;
    const int m0 = ty * 2, n0 = tx * 4;
    float acc[2][4] = {};
    for (int kt = 0; kt < 4; ++kt) {
#pragma unroll
        for (int r = 0; r < 8; ++r) {
            int row = r0 + r * 4;
            As[c0][row] = XC[(size_t)(bm * 32 + row) * 256 + kt * 64 + c0];
        }
#pragma unroll
        for (int r = 0; r < 16; ++r) {
            int row = r0 + r * 4;
            Bs[row][c0] = Wo[(kt * 64 + row) * 64 + c0];
        }
        __syncthreads();
#pragma unroll
        for (int kk = 0; kk < 64; ++kk) {
            float2 a = *(const float2*)&As[kk][m0];
            float4 b = *(const float4*)&Bs[kk][n0];
            acc[0][0] += a.x * b.x; acc[0][1] += a.x * b.y; acc[0][2] += a.x * b.z; acc[0][3] += a.x * b.w;
            acc[1][0] += a.y * b.x; acc[1][1] += a.y * b.y; acc[1][2] += a.y * b.z; acc[1][3] += a.y * b.w;
        }
        __syncthreads();
    }
#pragma unroll
    for (int i = 0; i < 2; ++i) {
        float4 v = make_float4(acc[i][0], acc[i][1], acc[i][2], acc[i][3]);
        *(float4*)&hc[(size_t)(bm * 32 + m0 + i) * 64 + n0] = v;
    }
#pragma unroll
    for (int i = 0; i < 2; ++i) {
        float p1 = 0.f, p2 = 0.f;
#pragma unroll
        for (int jj = 0; jj < 4; ++jj) {
            p1 += acc[i][jj] * aO[n0 + jj];
            p2 += acc[i][jj] * aO[64 + n0 + jj];
        }
#pragma unroll
        for (int off = 8; off; off >>= 1) {
            p1 += __shfl_xor(p1, off, 16);
            p2 += __shfl_xor(p2, off, 16);
        }
        if (tx == 0) {
            s1o[bm * 32 + m0 + i] = p1;
            s2o[bm * 32 + m0 + i] = p2;
        }
    }
}

// ---------------- lean bitonic sort: 1 block per task ----------------
__global__ __launch_bounds__(1024) void sort_k(const float* __restrict__ s2_all,
                                               int heads,
                                               float* __restrict__ g_sval,
                                               int* __restrict__ g_sidx,
                                               float* __restrict__ g_wN) {
    __shared__ unsigned long long sA[2][1024];
    __shared__ unsigned long long sB[2][1024];
    __shared__ float sM2;
    const int tid = threadIdx.x, t = blockIdx.x;
    const int g = t / heads, h = t % heads;
    const float* s2p = s2_all + (size_t)h * NTOT + (size_t)g * NSEG;

    unsigned long long a0 = pack_key(s2p[tid], tid);
    unsigned long long a1 = pack_key(s2p[tid + 1024], tid + 1024);
    int p = 0;
    for (int k = 2; k <= 2048; k <<= 1) {
        const bool up0 = (tid & k) == 0;
        const bool up1 = (((tid + 1024) & k) == 0);
        for (int j = k >> 1; j > 0; j >>= 1) {
            if (j >= 1024) {
                unsigned long long lo = a0 < a1 ? a0 : a1;
                unsigned long long hi = a0 < a1 ? a1 : a0;
                a0 = up0 ? lo : hi;
                a1 = up0 ? hi : lo;
            } else if (j >= 64) {
                sA[p][tid] = a0; sB[p][tid] = a1;
                __syncthreads();
                unsigned long long q0 = sA[p][tid ^ j], q1 = sB[p][tid ^ j];
                bool lower = (tid & j) == 0;
                a0 = ((a0 < q0) == (lower == up0)) ? a0 : q0;
                a1 = ((a1 < q1) == (lower == up1)) ? a1 : q1;
                p ^= 1;
            } else {
                unsigned long long q0 = shfl_xor_u64(a0, j);
                unsigned long long q1 = shfl_xor_u64(a1, j);
                bool lower = (tid & j) == 0;
                a0 = ((a0 < q0) == (lower == up0)) ? a0 : q0;
                a1 = ((a1 < q1) == (lower == up1)) ? a1 : q1;
            }
        }
    }
    float v0 = unpack_key(a0), v1 = unpack_key(a1);
    if (tid == 1023) sM2 = v1;
    __syncthreads();
    const float M2 = sM2;
    int i0 = (int)(unsigned)(a0 & 0xffffffffu);
    int i1 = (int)(unsigned)(a1 & 0xffffffffu);
    float w0 = __expf(0.2f * (v0 - M2));
    float w1 = __expf(0.2f * (v1 - M2));
    size_t o = (size_t)t * NSEG;
    g_sval[o + tid] = v0; g_sval[o + tid + 1024] = v1;
    g_sidx[o + tid] = i0; g_sidx[o + tid + 1024] = i1;
    g_wN[o + tid] = w0;   g_wN[o + tid + 1024] = w1;
}

// ---------------- wide table build: aligned AS rows + scalar arrays; XCD-clustered tasks ----------------
__global__ __launch_bounds__(256) void tabw_k(const float* __restrict__ V,
                                              int heads, int ntask,
                                              const int* __restrict__ g_sidx,
                                              const float* __restrict__ g_wN,
                                              float* __restrict__ AS,
                                              float* __restrict__ SCA, float* __restrict__ SCS,
                                              float* __restrict__ TAS,
                                              float* __restrict__ TSA, float* __restrict__ TSS) {
    const int L = blockIdx.x + (int)(gridDim.x * blockIdx.y);
    const int xcd = L & 7, slot = L >> 3;
    const int tpx = ntask >> 3;                    // tasks per XCD
    const int t = xcd * tpx + (slot >> 5);
    const int u = slot & 31;
    const int wv = threadIdx.x >> 6, lane = threadIdx.x & 63;
    const int c = u * 4 + wv, base = c * 16;
    const int g = t / heads, h = t % heads;
    const int seg = h * (ntask / heads) + g;       // V segment [seg][2048][64]
    const float* Vp = V + (size_t)seg * NSEG * 64;
    const int* sidx = g_sidx + (size_t)t * NSEG + base;
    const float* wnp = g_wN + (size_t)t * NSEG + base;
    float wn[16], vv[16];
#pragma unroll
    for (int j = 0; j < 16; ++j) wn[j] = wnp[j];
#pragma unroll
    for (int j = 0; j < 16; ++j) vv[j] = Vp[(size_t)sidx[j] * 64 + lane];
    float* ASp = AS + (size_t)t * NSEG * 128;
    // exclusive within-chunk prefix (A half of row)
    float accA = 0.f, scaA = 0.f;
#pragma unroll
    for (int j = 0; j < 16; ++j) {
        size_t pos = base + j;
        ASp[pos * 128 + lane] = accA;
        if (lane == 0) SCA[(size_t)t * NSEG + pos] = scaA;
        accA += wn[j] * vv[j]; scaA += wn[j];
    }
    TAS[((size_t)t * 128 + c) * 128 + lane] = accA;
    if (lane == 0) TSA[t * 128 + c] = scaA;
    // inclusive within-chunk suffix (S half of row)
    float accS = 0.f, scaS = 0.f;
#pragma unroll
    for (int j = 15; j >= 0; --j) {
        float w = wn[j], w2 = w * w, wp = w2 * w2 * w;
        accS += wp * vv[j]; scaS += wp;
        size_t pos = base + j;
        ASp[pos * 128 + 64 + lane] = accS;
        if (lane == 0) SCS[(size_t)t * NSEG + pos] = scaS;
    }
    TAS[((size_t)t * 128 + c) * 128 + 64 + lane] = accS;
    if (lane == 0) TSS[t * 128 + c] = scaS;
}

// ---------------- query: fused in-LDS chunk scan OVERLAPPED with bsearch + batched AS loads ----------------
template <int MODE>  // 0: ELU -> xc ; 1: ELU + log_softmax -> out
__global__ __launch_bounds__(1024) void query_k(const float* __restrict__ s1_all,
                                                float* __restrict__ out,
                                                int heads, int ntask, int ostride,
                                                const float* __restrict__ g_sval,
                                                const float* __restrict__ AS,
                                                const float* __restrict__ SCA, const float* __restrict__ SCS,
                                                const float* __restrict__ TAS,
                                                const float* __restrict__ TSA, const float* __restrict__ TSS) {
    __shared__ float sval[NSEG];        // 8 KB
    __shared__ float Ts[128 * 128];     // 64 KB: chunk rows, scanned in place
    __shared__ float totA[64];
    __shared__ float csa[132];
    __shared__ float css[132];
    const int tid = threadIdx.x;
    const int L = blockIdx.x;
    const int xcd = L & 7, slot = L >> 3;
    const int tpx = ntask >> 3;
    const int t = xcd * tpx + (slot >> 3);      // 8 blocks per task
    const int u = slot & 7;
    const int g = t / heads, h = t % heads;
    // stage sval + TAS slice
    const float4* sv4 = (const float4*)(g_sval + (size_t)t * NSEG);
    if (tid < 512) ((float4*)sval)[tid] = sv4[tid];
    const float4* Tg4 = (const float4*)(TAS + (size_t)t * 128 * 128);
    float4* Ts4 = (float4*)Ts;
#pragma unroll
    for (int i = 0; i < 4; ++i) Ts4[tid + i * 1024] = Tg4[tid + i * 1024];
    __syncthreads();

    // ---- overlap region: binary search + k_j shuffles + half-0 load issue (ALL waves)
    //      runs concurrently with the serial scan (threads 0-129); both drain at the next barrier ----
    const float M2 = sval[NSEG - 1];
    const int lane = tid & 63, wv = tid >> 6;       // 16 waves
    const int q0 = u * 256 + wv * 16;
    const float* s1p = s1_all + (size_t)h * NTOT + (size_t)g * NSEG;
    float* outp = out + (size_t)g * NSEG * ostride + h * 64;
    const float* ASp = AS + (size_t)t * NSEG * 128;
    const float* scA = SCA + (size_t)t * NSEG;
    const float* scS = SCS + (size_t)t * NSEG;
    int myq = q0 + (lane & 15);
    float s1v = s1p[myq];
    float th = -s1v;
    int lo = 0, hi = NSEG;
    while (lo < hi) { int mid = (lo + hi) >> 1; if (sval[mid] <= th) lo = mid + 1; else hi = mid; }
    int ks[16]; float s1qs[16];
#pragma unroll
    for (int j = 0; j < 16; ++j) { ks[j] = __shfl(lo, j, 64); s1qs[j] = __shfl(s1v, j, 64); }
    // half-0 batched loads (issued before the scan barrier; latency hides under scan)
    float rA[8], rS[8], sAv[8], sSv[8];
#pragma unroll
    for (int j = 0; j < 8; ++j) {
        int k = ks[j];
        if (k < NSEG) {
            const float* rowP = ASp + (size_t)k * 128;
            rA[j] = rowP[lane]; rS[j] = rowP[64 + lane];
            sAv[j] = scA[k]; sSv[j] = scS[k];
        } else { rA[j] = 0.f; rS[j] = 0.f; sAv[j] = 0.f; sSv[j] = 0.f; }
    }

    // ---- serial in-place scans (threads 0-129), order identical to R8 (absmax-preserving) ----
    if (tid < 64) {                 // A columns: exclusive prefix
        float run = 0.f;
        for (int c = 0; c < 128; ++c) { float v = Ts[c * 128 + tid]; Ts[c * 128 + tid] = run; run += v; }
        totA[tid] = run;
    } else if (tid < 128) {         // S columns: exclusive suffix
        float run = 0.f;
        for (int c = 127; c >= 0; --c) { float v = Ts[c * 128 + tid]; Ts[c * 128 + tid] = run; run += v; }
    } else if (tid == 128) {        // scalar A
        const float* TSAp = TSA + (size_t)t * 128;
        float run = 0.f;
        for (int c = 0; c < 128; ++c) { csa[c] = run; run += TSAp[c]; }
        csa[128] = run;
    } else if (tid == 129) {        // scalar S
        const float* TSSp = TSS + (size_t)t * 128;
        float run = 0.f;
        for (int c = 127; c >= 0; --c) { css[c] = run; run += TSSp[c]; }
    }
    __syncthreads();

    // ---- two halves of 8 queries; loads batched ahead of use ----
#pragma unroll
    for (int half = 0; half < 2; ++half) {
        if (half == 1) {
#pragma unroll
            for (int j = 0; j < 8; ++j) {
                int k = ks[8 + j];
                if (k < NSEG) {
                    const float* rowP = ASp + (size_t)k * 128;
                    rA[j] = rowP[lane]; rS[j] = rowP[64 + lane];
                    sAv[j] = scA[k]; sSv[j] = scS[k];
                } else { rA[j] = 0.f; rS[j] = 0.f; sAv[j] = 0.f; sSv[j] = 0.f; }
            }
        }
#pragma unroll
        for (int jj = 0; jj < 8; ++jj) {
            const int j = half * 8 + jj;
            const int k = ks[j];
            float s1q = s1qs[j];
            float accA, scaA, accS, scaS;
            if (k < NSEG) {
                const int c = k >> 4;
                accA = rA[jj] + Ts[c * 128 + lane];
                accS = rS[jj] + Ts[c * 128 + 64 + lane];
                scaA = sAv[jj] + csa[c];
                scaS = sSv[jj] + css[c];
            } else {
                accA = totA[lane]; scaA = csa[128];
                accS = 0.f; scaS = 0.f;
            }
            float cc = __expf(-0.8f * fmaxf(s1q + M2, 0.f));
            float o = (accS + cc * accA) / (scaS + cc * scaA);
            o = o > 0.f ? o : expm1f(o);  // ELU
            int q = q0 + j;
            if (MODE == 0) {
                outp[(size_t)q * ostride + lane] = o;
            } else {
                float m = o;
#pragma unroll
                for (int off = 32; off; off >>= 1) m = fmaxf(m, __shfl_xor(m, off, 64));
                float e = __expf(o - m);
#pragma unroll
                for (int off = 32; off; off >>= 1) e += __shfl_xor(e, off, 64);
                outp[(size_t)q * ostride + lane] = o - m - __logf(e);
            }
        }
    }
}

extern "C" void kernel_launch(void* const* d_in, const int* in_sizes, int n_in,
                              void* d_out, int out_size, void* d_ws, size_t ws_size,
                              hipStream_t stream) {
    const float* h_states = (const float*)d_in[0];
    const float* W_heads = (const float*)d_in[1];
    const float* a_heads = (const float*)d_in[2];
    const float* W_out = (const float*)d_in[3];
    const float* a_out = (const float*)d_in[4];
    float* w = (float*)d_ws;
    float* hh = w + OFF_HH;
    float* xc = w + OFF_XC;
    float* hc = w + OFF_HH;              // reuse: hh dead after tabw1
    float* s1h = w + OFF_S1H;
    float* s2h = w + OFF_S2H;
    float* s1o = w + OFF_S1O;
    float* s2o = w + OFF_S2O;
    float* g_sval = w + OFF_SVAL;
    float* g_wN = w + OFF_WN;
    int* g_sidx = (int*)(w + OFF_SIDX);
    float* SCA = w + OFF_SCA;
    float* SCS = w + OFF_SCS;
    float* AS = w + OFF_AS;
    float* TAS = w + OFF_TAS;
    float* TSA = w + OFF_TSA;
    float* TSS = w + OFF_TSS;
    float* outp = (float*)d_out;

    gemm1_k<<<dim3(256, 4), 256, 0, stream>>>(h_states, W_heads, a_heads, hh, s1h, s2h);
    sort_k<<<32, 1024, 0, stream>>>(s2h, 4, g_sval, g_sidx, g_wN);
    tabw_k<<<dim3(32, 32), 256, 0, stream>>>(hh, 4, 32, g_sidx, g_wN, AS, SCA, SCS, TAS, TSA, TSS);
    query_k<0><<<256, 1024, 0, stream>>>(s1h, xc, 4, 32, 256, g_sval, AS, SCA, SCS, TAS, TSA, TSS);
    gemm2_k<<<512, 256, 0, stream>>>(xc, W_out, a_out, hc, s1o, s2o);
    sort_k<<<8, 1024, 0, stream>>>(s2o, 1, g_sval, g_sidx, g_wN);
    tabw_k<<<dim3(32, 8), 256, 0, stream>>>(hc, 1, 8, g_sidx, g_wN, AS, SCA, SCS, TAS, TSA, TSS);
    query_k<1><<<64, 1024, 0, stream>>>(s1o, outp, 1, 8, 64, g_sval, AS, SCA, SCS, TAS, TSA, TSS);
}